// Round 1
// baseline (1034.822 us; speedup 1.0000x reference)
//
#include <hip/hip_runtime.h>
#include <hip/hip_bf16.h>

#define EPSQ 1e-7f

#define BSZ 128
#define M2 4608           // B*36 conv2 output positions
#define K2 20736          // 81*256
#define KSTEPS 648        // K2/32
#define KSPLIT 4

// ws offsets in floats (liveness-overlapped)
#define WS_CONV1 0              // 13107200 fl, dead after conv2
#define WS_CPART 13107200       // 4*4608*256 = 4718592 fl, dead after squash_pc
#define WS_UHAT  0              // 23592960 fl, written after CPART dead
#define WS_PC    23592960       // 1179648 fl
#define WS_V1    24772608       // 20480 fl
#define WS_C2    24793088       // 1474560 fl
#define WS_H0    26267648       // 20480 fl
#define WS_H1    26288128       // 65536 fl
#define WS_H2    26353664       // 131072 fl
// total 26484736 floats = ~106 MB

// ---------------- conv1: 28x28x1 -> 20x20x256, 9x9, stride 1, relu -------------
__global__ __launch_bounds__(256) void conv1_kernel(const float* __restrict__ img,
        const float* __restrict__ w1, const float* __restrict__ b1,
        float* __restrict__ out) {
    int bid = blockIdx.x;            // b*20 + oh
    int b = bid / 20, oh = bid % 20;
    __shared__ float simg[252];      // rows oh..oh+8, 28 wide
    int t = threadIdx.x;
    if (t < 252) simg[t] = img[b * 784 + oh * 28 + t];
    __syncthreads();
    float acc[20];
#pragma unroll
    for (int ow = 0; ow < 20; ++ow) acc[ow] = 0.f;
    for (int kh = 0; kh < 9; ++kh) {
#pragma unroll
        for (int kw = 0; kw < 9; ++kw) {
            float wv = w1[(kh * 9 + kw) * 256 + t];
            const float* sp = &simg[kh * 28 + kw];
#pragma unroll
            for (int ow = 0; ow < 20; ++ow) acc[ow] += sp[ow] * wv;
        }
    }
    float bias = b1[t];
    float* op = out + ((size_t)(b * 20 + oh) * 20) * 256 + t;
#pragma unroll
    for (int ow = 0; ow < 20; ++ow) op[ow * 256] = fmaxf(acc[ow] + bias, 0.f);
}

// -------- conv2 as im2col GEMM: [4608 x 20736] @ [20736 x 256], k-split ---------
__global__ __launch_bounds__(256) void conv2_gemm_kernel(const float* __restrict__ inp,
        const float* __restrict__ w2, float* __restrict__ part) {
    int nt = blockIdx.x;   // 0..3
    int mt = blockIdx.y;   // 0..71
    int ks = blockIdx.z;   // 0..KSPLIT-1
    int tid = threadIdx.x;
    int m0 = mt * 64, n0 = nt * 64;
    __shared__ float As[32][68];   // [kk][row], padded for b128-aligned reads
    __shared__ float Bs[32][64];   // [kk][n]

    // A loader: row = tid>>2, k-chunk of 8 at (tid&3)*8
    int arow = tid >> 2;
    int ak = (tid & 3) * 8;
    int m = m0 + arow;
    int b = m / 36, rem = m % 36;
    int ohh = rem / 6, oww = rem % 6;
    const float* inbase = inp + ((size_t)((b * 20 + 2 * ohh) * 20 + 2 * oww)) * 256;
    // B loader: k-row = tid>>3, 8 n's at (tid&7)*8
    int bk = tid >> 3;
    int bn = (tid & 7) * 8;
    int ty = tid >> 4, tx = tid & 15;

    float acc[4][4];
#pragma unroll
    for (int i = 0; i < 4; ++i)
#pragma unroll
        for (int j = 0; j < 4; ++j) acc[i][j] = 0.f;

    int kt0 = ks * (KSTEPS / KSPLIT);
    int kt1 = kt0 + (KSTEPS / KSPLIT);
    for (int kt = kt0; kt < kt1; ++kt) {
        int kbase = kt * 32;
        int khkw = kbase >> 8;           // 32 | 256 so each step is one (kh,kw)
        int kh = khkw / 9, kw = khkw % 9;
        int ic = (kbase & 255) + ak;
        const float* ap = inbase + (kh * 20 + kw) * 256 + ic;
        float4 a0 = *(const float4*)(ap);
        float4 a1 = *(const float4*)(ap + 4);
        const float* bp = w2 + (size_t)(kbase + bk) * 256 + n0 + bn;
        float4 b0 = *(const float4*)(bp);
        float4 b1 = *(const float4*)(bp + 4);
        __syncthreads();
        As[ak + 0][arow] = a0.x; As[ak + 1][arow] = a0.y;
        As[ak + 2][arow] = a0.z; As[ak + 3][arow] = a0.w;
        As[ak + 4][arow] = a1.x; As[ak + 5][arow] = a1.y;
        As[ak + 6][arow] = a1.z; As[ak + 7][arow] = a1.w;
        *(float4*)&Bs[bk][bn] = b0;
        *(float4*)&Bs[bk][bn + 4] = b1;
        __syncthreads();
#pragma unroll
        for (int kk = 0; kk < 32; ++kk) {
            float4 av = *(const float4*)&As[kk][ty * 4];
            float4 bv = *(const float4*)&Bs[kk][tx * 4];
            acc[0][0] += av.x * bv.x; acc[0][1] += av.x * bv.y;
            acc[0][2] += av.x * bv.z; acc[0][3] += av.x * bv.w;
            acc[1][0] += av.y * bv.x; acc[1][1] += av.y * bv.y;
            acc[1][2] += av.y * bv.z; acc[1][3] += av.y * bv.w;
            acc[2][0] += av.z * bv.x; acc[2][1] += av.z * bv.y;
            acc[2][2] += av.z * bv.z; acc[2][3] += av.z * bv.w;
            acc[3][0] += av.w * bv.x; acc[3][1] += av.w * bv.y;
            acc[3][2] += av.w * bv.z; acc[3][3] += av.w * bv.w;
        }
    }
    float* op = part + ((size_t)ks * M2 + m0 + ty * 4) * 256 + n0 + tx * 4;
#pragma unroll
    for (int i = 0; i < 4; ++i)
#pragma unroll
        for (int j = 0; j < 4; ++j) op[(size_t)i * 256 + j] = acc[i][j];
}

// -------- reduce k-split partials + bias + relu + squash(8) -> pc ---------------
__global__ __launch_bounds__(256) void squash_pc_kernel(const float* __restrict__ part,
        const float* __restrict__ b2, float* __restrict__ pc) {
    int m = blockIdx.x;
    int n = threadIdx.x;
    size_t idx = (size_t)m * 256 + n;
    const size_t stride = (size_t)M2 * 256;
    float v = part[idx] + part[idx + stride] + part[idx + 2 * stride] + part[idx + 3 * stride];
    v = fmaxf(v + b2[n], 0.f);
    float sq = v * v;
    sq += __shfl_xor(sq, 1, 8);
    sq += __shfl_xor(sq, 2, 8);
    sq += __shfl_xor(sq, 4, 8);
    float scale = sq / ((1.f + sq) * sqrtf(sq + EPSQ));
    pc[idx] = v * scale;
}

// -------- u_hat[b,i,jd] = sum_k W[i,jd,k] * pc[b,i,k] ---------------------------
__global__ __launch_bounds__(256) void uhat_kernel(const float* __restrict__ Wm,
        const float* __restrict__ pc, float* __restrict__ uhat) {
    int i = blockIdx.x;
    int t = threadIdx.x;
    __shared__ float Wl[1280];
    __shared__ float pcl[1024];
    for (int r = t; r < 1280; r += 256) Wl[r] = Wm[(size_t)i * 1280 + r];
    for (int r = t; r < 1024; r += 256)
        pcl[r] = pc[(size_t)(r >> 3) * 9216 + i * 8 + (r & 7)];
    __syncthreads();
    for (int r = 0; r < 80; ++r) {
        int o = r * 256 + t;
        int b = o / 160, jd = o % 160;
        const float* wp = &Wl[jd * 8];
        const float* pp = &pcl[b * 8];
        float acc = 0.f;
#pragma unroll
        for (int k = 0; k < 8; ++k) acc += wp[k] * pp[k];
        uhat[((size_t)b * 1152 + i) * 160 + jd] = acc;
    }
}

// -------- round 1: s1 = 0.1*sum_i u_hat ; v1 = squash_d(s1) ---------------------
__global__ __launch_bounds__(192) void s1v1_kernel(const float* __restrict__ uhat,
        float* __restrict__ v1) {
    int b = blockIdx.x, t = threadIdx.x;
    if (t >= 160) return;
    const float* up = uhat + (size_t)b * 1152 * 160 + t;
    float s = 0.f;
    for (int i = 0; i < 1152; ++i) s += up[(size_t)i * 160];
    s *= 0.1f;
    float sq = s * s;
    sq += __shfl_xor(sq, 1, 16);
    sq += __shfl_xor(sq, 2, 16);
    sq += __shfl_xor(sq, 4, 16);
    sq += __shfl_xor(sq, 8, 16);
    float v = s * sq / ((1.f + sq) * sqrtf(sq + EPSQ));
    v1[b * 160 + t] = v;
}

// -------- agreement + softmax over j -> c2 --------------------------------------
__global__ __launch_bounds__(128) void c2_kernel(const float* __restrict__ uhat,
        const float* __restrict__ v1, float* __restrict__ c2) {
    int b = blockIdx.y;
    int i = blockIdx.x * 128 + threadIdx.x;
    int t = threadIdx.x;
    __shared__ float v1s[160];
    v1s[t] = v1[b * 160 + t];
    if (t < 32) v1s[128 + t] = v1[b * 160 + 128 + t];
    __syncthreads();
    const float* up = uhat + ((size_t)b * 1152 + i) * 160;
    float uv[10];
#pragma unroll
    for (int j = 0; j < 10; ++j) {
        float a = 0.f;
#pragma unroll
        for (int d = 0; d < 16; ++d) a += up[j * 16 + d] * v1s[j * 16 + d];
        uv[j] = a;
    }
    float mx = uv[0];
#pragma unroll
    for (int j = 1; j < 10; ++j) mx = fmaxf(mx, uv[j]);
    float sum = 0.f;
#pragma unroll
    for (int j = 0; j < 10; ++j) { uv[j] = expf(uv[j] - mx); sum += uv[j]; }
    float inv = 1.f / sum;
    float* cp = c2 + ((size_t)b * 1152 + i) * 10;
#pragma unroll
    for (int j = 0; j < 10; ++j) cp[j] = uv[j] * inv;
}

// -------- s2, v2, norms, argmax, masked decoder input ---------------------------
__global__ __launch_bounds__(192) void s2v2_kernel(const float* __restrict__ uhat,
        const float* __restrict__ c2, const int* __restrict__ target,
        float* __restrict__ out, float* __restrict__ h0) {
    int b = blockIdx.x, t = threadIdx.x;
    int j = t >> 4;
    __shared__ float nrm[10];
    float v = 0.f;
    if (t < 160) {
        const float* up = uhat + (size_t)b * 1152 * 160 + t;
        const float* cp = c2 + (size_t)b * 1152 * 10 + j;
        float s = 0.f;
        for (int i = 0; i < 1152; ++i) s += cp[(size_t)i * 10] * up[(size_t)i * 160];
        float sq = s * s;
        sq += __shfl_xor(sq, 1, 16);
        sq += __shfl_xor(sq, 2, 16);
        sq += __shfl_xor(sq, 4, 16);
        sq += __shfl_xor(sq, 8, 16);
        v = s * sq / ((1.f + sq) * sqrtf(sq + EPSQ));
        float vsq = v * v;
        vsq += __shfl_xor(vsq, 1, 16);
        vsq += __shfl_xor(vsq, 2, 16);
        vsq += __shfl_xor(vsq, 4, 16);
        vsq += __shfl_xor(vsq, 8, 16);
        float norm = sqrtf(vsq + EPSQ);
        if ((t & 15) == 0) { nrm[j] = norm; out[b * 10 + j] = norm; }
    }
    __syncthreads();
    if (t == 0) {
        float best = nrm[0]; int am = 0;
#pragma unroll
        for (int jj = 1; jj < 10; ++jj) if (nrm[jj] > best) { best = nrm[jj]; am = jj; }
        out[1280 + b] = (float)am;
    }
    if (t < 160) h0[b * 160 + t] = (j == target[b]) ? v : 0.f;
}

// -------- dense layers: relu (ACT=0) or sigmoid (ACT=1) -------------------------
template <int KDIM, int ACT>
__global__ __launch_bounds__(256) void fc_kernel(const float* __restrict__ in,
        const float* __restrict__ w, const float* __restrict__ bias,
        float* __restrict__ out, int N) {
    int b = blockIdx.y;
    int n = blockIdx.x * 256 + threadIdx.x;
    __shared__ float sk[KDIM];
    for (int r = threadIdx.x; r < KDIM; r += 256) sk[r] = in[(size_t)b * KDIM + r];
    __syncthreads();
    if (n >= N) return;
    float acc = bias[n];
    for (int k = 0; k < KDIM; ++k) acc += sk[k] * w[(size_t)k * N + n];
    if (ACT == 0) acc = fmaxf(acc, 0.f);
    else acc = 1.f / (1.f + expf(-acc));
    out[(size_t)b * N + n] = acc;
}

extern "C" void kernel_launch(void* const* d_in, const int* in_sizes, int n_in,
                              void* d_out, int out_size, void* d_ws, size_t ws_size,
                              hipStream_t stream) {
    const float* image = (const float*)d_in[0];
    const int*   target = (const int*)d_in[1];
    const float* w1  = (const float*)d_in[2];
    const float* b1  = (const float*)d_in[3];
    const float* w2  = (const float*)d_in[4];
    const float* b2  = (const float*)d_in[5];
    const float* Wm  = (const float*)d_in[6];
    const float* d1w = (const float*)d_in[7];
    const float* d1b = (const float*)d_in[8];
    const float* d2w = (const float*)d_in[9];
    const float* d2b = (const float*)d_in[10];
    const float* dow = (const float*)d_in[11];
    const float* dob = (const float*)d_in[12];
    float* out = (float*)d_out;
    float* ws  = (float*)d_ws;

    conv1_kernel<<<2560, 256, 0, stream>>>(image, w1, b1, ws + WS_CONV1);
    conv2_gemm_kernel<<<dim3(4, 72, KSPLIT), 256, 0, stream>>>(ws + WS_CONV1, w2, ws + WS_CPART);
    squash_pc_kernel<<<4608, 256, 0, stream>>>(ws + WS_CPART, b2, ws + WS_PC);
    uhat_kernel<<<1152, 256, 0, stream>>>(Wm, ws + WS_PC, ws + WS_UHAT);
    s1v1_kernel<<<128, 192, 0, stream>>>(ws + WS_UHAT, ws + WS_V1);
    c2_kernel<<<dim3(9, 128), 128, 0, stream>>>(ws + WS_UHAT, ws + WS_V1, ws + WS_C2);
    s2v2_kernel<<<128, 192, 0, stream>>>(ws + WS_UHAT, ws + WS_C2, target, out, ws + WS_H0);
    fc_kernel<160, 0><<<dim3(2, 128), 256, 0, stream>>>(ws + WS_H0, d1w, d1b, ws + WS_H1, 512);
    fc_kernel<512, 0><<<dim3(4, 128), 256, 0, stream>>>(ws + WS_H1, d2w, d2b, ws + WS_H2, 1024);
    fc_kernel<1024, 1><<<dim3(4, 128), 256, 0, stream>>>(ws + WS_H2, dow, dob, out + 1408, 784);
}

// Round 2
// 592.445 us; speedup vs baseline: 1.7467x; 1.7467x over previous
//
#include <hip/hip_runtime.h>
#include <hip/hip_bf16.h>

#define EPSQ 1e-7f

#define BSZ 128
#define M2 4608           // B*36 conv2 output positions
#define K2 20736          // 81*256
#define KSTEPS 648        // K2/32
#define KSPLIT 4

// ws offsets in floats (liveness-overlapped; total 26,484,736 fl = 106 MB,
// same footprint round 1 proved safe)
#define WS_UHAT  0              // 23,592,960 fl; written after everything below dies
#define WS_C1H   0              // 13,107,200 ushort = 6,553,600 fl (conv1 bf16 hi)
#define WS_C1L   6553600        // conv1 bf16 lo
#define WS_W2TH  13107200       // 5,308,416 ushort = 2,654,208 fl (w2^T bf16 hi)
#define WS_W2TL  15761408
#define WS_CPART 18415616       // 4*4608*256 fl = 4,718,592 (ends 23,134,208 < UHAT end)
#define WS_PC    23592960       // 1,179,648 fl
#define WS_V1    24772608
#define WS_C2    24793088
#define WS_H0    26267648
#define WS_H1    26288128
#define WS_H2    26353664

typedef __attribute__((ext_vector_type(8))) short short8;
typedef __attribute__((ext_vector_type(4))) float floatx4;

__device__ inline ushort bf16_rne(float x) {
    union { float f; unsigned u; } v; v.f = x;
    unsigned r = v.u + 0x7FFFu + ((v.u >> 16) & 1u);
    return (ushort)(r >> 16);
}
__device__ inline float bf16_to_f(ushort h) {
    union { unsigned u; float f; } v; v.u = ((unsigned)h) << 16;
    return v.f;
}

// ---------------- conv1: 28x28x1 -> 20x20x256, relu, emit bf16 hi/lo -----------
__global__ __launch_bounds__(256) void conv1_kernel(const float* __restrict__ img,
        const float* __restrict__ w1, const float* __restrict__ b1,
        ushort* __restrict__ c1h, ushort* __restrict__ c1l) {
    int bid = blockIdx.x;            // b*20 + oh
    int b = bid / 20, oh = bid % 20;
    __shared__ float simg[252];
    int t = threadIdx.x;
    if (t < 252) simg[t] = img[b * 784 + oh * 28 + t];
    __syncthreads();
    float acc[20];
#pragma unroll
    for (int ow = 0; ow < 20; ++ow) acc[ow] = 0.f;
    for (int kh = 0; kh < 9; ++kh) {
#pragma unroll
        for (int kw = 0; kw < 9; ++kw) {
            float wv = w1[(kh * 9 + kw) * 256 + t];
            const float* sp = &simg[kh * 28 + kw];
#pragma unroll
            for (int ow = 0; ow < 20; ++ow) acc[ow] += sp[ow] * wv;
        }
    }
    float bias = b1[t];
    size_t opos = ((size_t)(b * 20 + oh) * 20) * 256 + t;
#pragma unroll
    for (int ow = 0; ow < 20; ++ow) {
        float x = fmaxf(acc[ow] + bias, 0.f);
        ushort h = bf16_rne(x);
        c1h[opos + (size_t)ow * 256] = h;
        c1l[opos + (size_t)ow * 256] = bf16_rne(x - bf16_to_f(h));
    }
}

// -------- w2 [20736][256] fp32 -> w2t hi/lo [256][20736] bf16 -------------------
__global__ __launch_bounds__(256) void prep_w2t_kernel(const float* __restrict__ w2,
        ushort* __restrict__ w2th, ushort* __restrict__ w2tl) {
    int kt = blockIdx.x, nt = blockIdx.y;   // 324 x 4
    __shared__ float tile[64][65];
    int t = threadIdx.x;
    int tn = t & 63, t4 = t >> 6;
#pragma unroll
    for (int i = 0; i < 16; ++i) {
        int k = i * 4 + t4;
        tile[k][tn] = w2[(size_t)(kt * 64 + k) * 256 + nt * 64 + tn];
    }
    __syncthreads();
    int tk = t & 63;
#pragma unroll
    for (int i = 0; i < 16; ++i) {
        int n = i * 4 + t4;
        float x = tile[tk][n];
        ushort h = bf16_rne(x);
        ushort lo = bf16_rne(x - bf16_to_f(h));
        size_t o = (size_t)(nt * 64 + n) * 20736 + kt * 64 + tk;
        w2th[o] = h; w2tl[o] = lo;
    }
}

// -------- conv2 MFMA GEMM: split bf16 (hi/lo, 3 terms), fp32 partials -----------
// BM=64, BN=128, BK=32, grid (NT=2, MT=72, KSPLIT=4), 4 waves/block
#define AH_OFF 0
#define AL_OFF 2560
#define BH_OFF 5120
#define BL_OFF 10240
__global__ __launch_bounds__(256) void conv2_mfma_kernel(
        const ushort* __restrict__ c1h, const ushort* __restrict__ c1l,
        const ushort* __restrict__ w2th, const ushort* __restrict__ w2tl,
        float* __restrict__ part) {
    int nt = blockIdx.x, mt = blockIdx.y, ks = blockIdx.z;
    int t = threadIdx.x;
    int m0 = mt * 64, n0 = nt * 128;
    __shared__ ushort lds[15360];    // A[64][40] hi/lo + Bt[128][40] hi/lo (pad->free reads)

    // staging: each thread stages one 16B chunk of A-hi/A-lo, two of B-hi/B-lo
    int srow = t >> 2;               // 0..63
    int schunk8 = (t & 3) * 8;
    int m = m0 + srow;
    int b = m / 36, rem = m % 36;
    int posbase = ((b * 20 + (rem / 6) * 2) * 20 + (rem % 6) * 2) * 256;
    size_t bbase0 = (size_t)(n0 + srow) * 20736 + schunk8;
    size_t bbase1 = bbase0 + (size_t)64 * 20736;

    int lane = t & 63, wave = t >> 6;
    int l15 = lane & 15, kc8 = (lane >> 4) * 8;
    int wrb = (wave >> 1) * 32, wcb = (wave & 1) * 64;

    floatx4 acc[2][4];
#pragma unroll
    for (int mi = 0; mi < 2; ++mi)
#pragma unroll
        for (int nj = 0; nj < 4; ++nj) acc[mi][nj] = (floatx4)0.f;

    int kt0 = ks * (KSTEPS / KSPLIT);
    for (int kt = kt0; kt < kt0 + KSTEPS / KSPLIT; ++kt) {
        int kbase = kt * 32;
        int khkw = kbase >> 8;                  // 32 | 256: one (kh,kw) per step
        int kh = khkw / 9, kw = khkw - kh * 9;
        int aoff = posbase + (kh * 20 + kw) * 256 + (kbase & 255) + schunk8;
        uint4 vah = *(const uint4*)(c1h + aoff);
        uint4 val = *(const uint4*)(c1l + aoff);
        uint4 vbh0 = *(const uint4*)(w2th + bbase0 + kbase);
        uint4 vbh1 = *(const uint4*)(w2th + bbase1 + kbase);
        uint4 vbl0 = *(const uint4*)(w2tl + bbase0 + kbase);
        uint4 vbl1 = *(const uint4*)(w2tl + bbase1 + kbase);
        __syncthreads();
        int sw = srow * 40 + schunk8;
        *(uint4*)&lds[AH_OFF + sw] = vah;
        *(uint4*)&lds[AL_OFF + sw] = val;
        *(uint4*)&lds[BH_OFF + sw] = vbh0;
        *(uint4*)&lds[BH_OFF + sw + 64 * 40] = vbh1;
        *(uint4*)&lds[BL_OFF + sw] = vbl0;
        *(uint4*)&lds[BL_OFF + sw + 64 * 40] = vbl1;
        __syncthreads();

        short8 ah[2], al[2], bh[4], bl[4];
#pragma unroll
        for (int mi = 0; mi < 2; ++mi) {
            int r = wrb + mi * 16 + l15;
            ah[mi] = *(const short8*)&lds[AH_OFF + r * 40 + kc8];
            al[mi] = *(const short8*)&lds[AL_OFF + r * 40 + kc8];
        }
#pragma unroll
        for (int nj = 0; nj < 4; ++nj) {
            int c = wcb + nj * 16 + l15;
            bh[nj] = *(const short8*)&lds[BH_OFF + c * 40 + kc8];
            bl[nj] = *(const short8*)&lds[BL_OFF + c * 40 + kc8];
        }
#pragma unroll
        for (int mi = 0; mi < 2; ++mi)
#pragma unroll
            for (int nj = 0; nj < 4; ++nj) {
                acc[mi][nj] = __builtin_amdgcn_mfma_f32_16x16x32_bf16(ah[mi], bh[nj], acc[mi][nj], 0, 0, 0);
                acc[mi][nj] = __builtin_amdgcn_mfma_f32_16x16x32_bf16(ah[mi], bl[nj], acc[mi][nj], 0, 0, 0);
                acc[mi][nj] = __builtin_amdgcn_mfma_f32_16x16x32_bf16(al[mi], bh[nj], acc[mi][nj], 0, 0, 0);
            }
    }
    // epilogue: C/D layout col=lane&15, row=(lane>>4)*4+reg
    size_t obase = (size_t)ks * M2 * 256;
#pragma unroll
    for (int mi = 0; mi < 2; ++mi)
#pragma unroll
        for (int nj = 0; nj < 4; ++nj) {
            int col = n0 + wcb + nj * 16 + l15;
            int rowb = m0 + wrb + mi * 16 + (lane >> 4) * 4;
#pragma unroll
            for (int r = 0; r < 4; ++r)
                part[obase + (size_t)(rowb + r) * 256 + col] = acc[mi][nj][r];
        }
}

// -------- reduce k-split partials + bias + relu + squash(8) -> pc ---------------
__global__ __launch_bounds__(256) void squash_pc_kernel(const float* __restrict__ part,
        const float* __restrict__ b2, float* __restrict__ pc) {
    int m = blockIdx.x;
    int n = threadIdx.x;
    size_t idx = (size_t)m * 256 + n;
    const size_t stride = (size_t)M2 * 256;
    float v = part[idx] + part[idx + stride] + part[idx + 2 * stride] + part[idx + 3 * stride];
    v = fmaxf(v + b2[n], 0.f);
    float sq = v * v;
    sq += __shfl_xor(sq, 1, 8);
    sq += __shfl_xor(sq, 2, 8);
    sq += __shfl_xor(sq, 4, 8);
    float scale = sq / ((1.f + sq) * sqrtf(sq + EPSQ));
    pc[idx] = v * scale;
}

// -------- u_hat[b,i,jd] = sum_k W[i,jd,k] * pc[b,i,k] ---------------------------
__global__ __launch_bounds__(256) void uhat_kernel(const float* __restrict__ Wm,
        const float* __restrict__ pc, float* __restrict__ uhat) {
    int i = blockIdx.x;
    int t = threadIdx.x;
    __shared__ float Wl[1280];
    __shared__ float pcl[1024];
    for (int r = t; r < 1280; r += 256) Wl[r] = Wm[(size_t)i * 1280 + r];
    for (int r = t; r < 1024; r += 256)
        pcl[r] = pc[(size_t)(r >> 3) * 9216 + i * 8 + (r & 7)];
    __syncthreads();
    for (int r = 0; r < 80; ++r) {
        int o = r * 256 + t;
        int b = o / 160, jd = o % 160;
        const float* wp = &Wl[jd * 8];
        const float* pp = &pcl[b * 8];
        float acc = 0.f;
#pragma unroll
        for (int k = 0; k < 8; ++k) acc += wp[k] * pp[k];
        uhat[((size_t)b * 1152 + i) * 160 + jd] = acc;
    }
}

// -------- round 1: s1 = 0.1*sum_i u_hat ; v1 = squash_d(s1) ---------------------
__global__ __launch_bounds__(192) void s1v1_kernel(const float* __restrict__ uhat,
        float* __restrict__ v1) {
    int b = blockIdx.x, t = threadIdx.x;
    if (t >= 160) return;
    const float* up = uhat + (size_t)b * 1152 * 160 + t;
    float s = 0.f;
    for (int i = 0; i < 1152; ++i) s += up[(size_t)i * 160];
    s *= 0.1f;
    float sq = s * s;
    sq += __shfl_xor(sq, 1, 16);
    sq += __shfl_xor(sq, 2, 16);
    sq += __shfl_xor(sq, 4, 16);
    sq += __shfl_xor(sq, 8, 16);
    float v = s * sq / ((1.f + sq) * sqrtf(sq + EPSQ));
    v1[b * 160 + t] = v;
}

// -------- agreement + softmax over j -> c2 --------------------------------------
__global__ __launch_bounds__(128) void c2_kernel(const float* __restrict__ uhat,
        const float* __restrict__ v1, float* __restrict__ c2) {
    int b = blockIdx.y;
    int i = blockIdx.x * 128 + threadIdx.x;
    int t = threadIdx.x;
    __shared__ float v1s[160];
    v1s[t] = v1[b * 160 + t];
    if (t < 32) v1s[128 + t] = v1[b * 160 + 128 + t];
    __syncthreads();
    const float* up = uhat + ((size_t)b * 1152 + i) * 160;
    float uv[10];
#pragma unroll
    for (int j = 0; j < 10; ++j) {
        float a = 0.f;
#pragma unroll
        for (int d = 0; d < 16; ++d) a += up[j * 16 + d] * v1s[j * 16 + d];
        uv[j] = a;
    }
    float mx = uv[0];
#pragma unroll
    for (int j = 1; j < 10; ++j) mx = fmaxf(mx, uv[j]);
    float sum = 0.f;
#pragma unroll
    for (int j = 0; j < 10; ++j) { uv[j] = expf(uv[j] - mx); sum += uv[j]; }
    float inv = 1.f / sum;
    float* cp = c2 + ((size_t)b * 1152 + i) * 10;
#pragma unroll
    for (int j = 0; j < 10; ++j) cp[j] = uv[j] * inv;
}

// -------- s2, v2, norms, argmax, masked decoder input ---------------------------
__global__ __launch_bounds__(192) void s2v2_kernel(const float* __restrict__ uhat,
        const float* __restrict__ c2, const int* __restrict__ target,
        float* __restrict__ out, float* __restrict__ h0) {
    int b = blockIdx.x, t = threadIdx.x;
    int j = t >> 4;
    __shared__ float nrm[10];
    float v = 0.f;
    if (t < 160) {
        const float* up = uhat + (size_t)b * 1152 * 160 + t;
        const float* cp = c2 + (size_t)b * 1152 * 10 + j;
        float s = 0.f;
        for (int i = 0; i < 1152; ++i) s += cp[(size_t)i * 10] * up[(size_t)i * 160];
        float sq = s * s;
        sq += __shfl_xor(sq, 1, 16);
        sq += __shfl_xor(sq, 2, 16);
        sq += __shfl_xor(sq, 4, 16);
        sq += __shfl_xor(sq, 8, 16);
        v = s * sq / ((1.f + sq) * sqrtf(sq + EPSQ));
        float vsq = v * v;
        vsq += __shfl_xor(vsq, 1, 16);
        vsq += __shfl_xor(vsq, 2, 16);
        vsq += __shfl_xor(vsq, 4, 16);
        vsq += __shfl_xor(vsq, 8, 16);
        float norm = sqrtf(vsq + EPSQ);
        if ((t & 15) == 0) { nrm[j] = norm; out[b * 10 + j] = norm; }
    }
    __syncthreads();
    if (t == 0) {
        float best = nrm[0]; int am = 0;
#pragma unroll
        for (int jj = 1; jj < 10; ++jj) if (nrm[jj] > best) { best = nrm[jj]; am = jj; }
        out[1280 + b] = (float)am;
    }
    if (t < 160) h0[b * 160 + t] = (j == target[b]) ? v : 0.f;
}

// -------- dense layers: relu (ACT=0) or sigmoid (ACT=1) -------------------------
template <int KDIM, int ACT>
__global__ __launch_bounds__(256) void fc_kernel(const float* __restrict__ in,
        const float* __restrict__ w, const float* __restrict__ bias,
        float* __restrict__ out, int N) {
    int b = blockIdx.y;
    int n = blockIdx.x * 256 + threadIdx.x;
    __shared__ float sk[KDIM];
    for (int r = threadIdx.x; r < KDIM; r += 256) sk[r] = in[(size_t)b * KDIM + r];
    __syncthreads();
    if (n >= N) return;
    float acc = bias[n];
    for (int k = 0; k < KDIM; ++k) acc += sk[k] * w[(size_t)k * N + n];
    if (ACT == 0) acc = fmaxf(acc, 0.f);
    else acc = 1.f / (1.f + expf(-acc));
    out[(size_t)b * N + n] = acc;
}

extern "C" void kernel_launch(void* const* d_in, const int* in_sizes, int n_in,
                              void* d_out, int out_size, void* d_ws, size_t ws_size,
                              hipStream_t stream) {
    const float* image = (const float*)d_in[0];
    const int*   target = (const int*)d_in[1];
    const float* w1  = (const float*)d_in[2];
    const float* b1  = (const float*)d_in[3];
    const float* w2  = (const float*)d_in[4];
    const float* b2  = (const float*)d_in[5];
    const float* Wm  = (const float*)d_in[6];
    const float* d1w = (const float*)d_in[7];
    const float* d1b = (const float*)d_in[8];
    const float* d2w = (const float*)d_in[9];
    const float* d2b = (const float*)d_in[10];
    const float* dow = (const float*)d_in[11];
    const float* dob = (const float*)d_in[12];
    float* out = (float*)d_out;
    float* ws  = (float*)d_ws;

    ushort* c1h  = (ushort*)(ws + WS_C1H);
    ushort* c1l  = (ushort*)(ws + WS_C1L);
    ushort* w2th = (ushort*)(ws + WS_W2TH);
    ushort* w2tl = (ushort*)(ws + WS_W2TL);

    conv1_kernel<<<2560, 256, 0, stream>>>(image, w1, b1, c1h, c1l);
    prep_w2t_kernel<<<dim3(324, 4), 256, 0, stream>>>(w2, w2th, w2tl);
    conv2_mfma_kernel<<<dim3(2, 72, KSPLIT), 256, 0, stream>>>(c1h, c1l, w2th, w2tl, ws + WS_CPART);
    squash_pc_kernel<<<4608, 256, 0, stream>>>(ws + WS_CPART, b2, ws + WS_PC);
    uhat_kernel<<<1152, 256, 0, stream>>>(Wm, ws + WS_PC, ws + WS_UHAT);
    s1v1_kernel<<<128, 192, 0, stream>>>(ws + WS_UHAT, ws + WS_V1);
    c2_kernel<<<dim3(9, 128), 128, 0, stream>>>(ws + WS_UHAT, ws + WS_V1, ws + WS_C2);
    s2v2_kernel<<<128, 192, 0, stream>>>(ws + WS_UHAT, ws + WS_C2, target, out, ws + WS_H0);
    fc_kernel<160, 0><<<dim3(2, 128), 256, 0, stream>>>(ws + WS_H0, d1w, d1b, ws + WS_H1, 512);
    fc_kernel<512, 0><<<dim3(4, 128), 256, 0, stream>>>(ws + WS_H1, d2w, d2b, ws + WS_H2, 1024);
    fc_kernel<1024, 1><<<dim3(4, 128), 256, 0, stream>>>(ws + WS_H2, dow, dob, out + 1408, 784);
}